// Round 1
// baseline (120.720 us; speedup 1.0000x reference)
//
#include <hip/hip_runtime.h>

// Trilinear grid_sample (align_corners=False, padding zeros) of a 256^3 fp32
// volume at B*N random points, scaled by 100.
//
// coords = x / 0.5 = x*2 (exact); ix = ((gx+1)*256 - 1)*0.5, same for y,z.
// Validity is folded into per-axis weight factors (zeroed when the index is
// out of range), indices clamped for the fetch — identical to the reference's
// per-corner where(valid, v, 0).

#define RES 256

__global__ __launch_bounds__(256) void VolumeExplicit_29257317220866_kernel(
    const float* __restrict__ x,
    const float* __restrict__ vol,
    float* __restrict__ out,
    int n)
{
    int i = blockIdx.x * blockDim.x + threadIdx.x;
    if (i >= n) return;

    // load 3 coords (stride-3; wave reads a contiguous 768B region)
    float gx = x[3 * i + 0] * 2.0f;
    float gy = x[3 * i + 1] * 2.0f;
    float gz = x[3 * i + 2] * 2.0f;

    // unnormalize, align_corners=False (match reference expression order)
    float ix = ((gx + 1.0f) * (float)RES - 1.0f) * 0.5f;
    float iy = ((gy + 1.0f) * (float)RES - 1.0f) * 0.5f;
    float iz = ((gz + 1.0f) * (float)RES - 1.0f) * 0.5f;

    float x0f = floorf(ix), y0f = floorf(iy), z0f = floorf(iz);
    float tx = ix - x0f, ty = iy - y0f, tz = iz - z0f;

    int x0 = (int)x0f, y0 = (int)y0f, z0 = (int)z0f;
    int x1 = x0 + 1, y1 = y0 + 1, z1 = z0 + 1;

    // per-axis weights, zeroed when that index is out of bounds
    float wx0 = (x0 >= 0 && x0 < RES) ? (1.0f - tx) : 0.0f;
    float wx1 = (x1 >= 0 && x1 < RES) ? tx : 0.0f;
    float wy0 = (y0 >= 0 && y0 < RES) ? (1.0f - ty) : 0.0f;
    float wy1 = (y1 >= 0 && y1 < RES) ? ty : 0.0f;
    float wz0 = (z0 >= 0 && z0 < RES) ? (1.0f - tz) : 0.0f;
    float wz1 = (z1 >= 0 && z1 < RES) ? tz : 0.0f;

    // clamped indices (safe fetch; zero weight kills invalid contributions)
    int xc0 = min(max(x0, 0), RES - 1), xc1 = min(max(x1, 0), RES - 1);
    int yc0 = min(max(y0, 0), RES - 1), yc1 = min(max(y1, 0), RES - 1);
    int zc0 = min(max(z0, 0), RES - 1), zc1 = min(max(z1, 0), RES - 1);

    // flat offsets; issue all 8 loads back-to-back for MLP
    int r00 = (zc0 * RES + yc0) * RES;
    int r01 = (zc0 * RES + yc1) * RES;
    int r10 = (zc1 * RES + yc0) * RES;
    int r11 = (zc1 * RES + yc1) * RES;

    float v000 = vol[r00 + xc0];
    float v001 = vol[r00 + xc1];
    float v010 = vol[r01 + xc0];
    float v011 = vol[r01 + xc1];
    float v100 = vol[r10 + xc0];
    float v101 = vol[r10 + xc1];
    float v110 = vol[r11 + xc0];
    float v111 = vol[r11 + xc1];

    float c00 = v000 * wx0 + v001 * wx1;
    float c01 = v010 * wx0 + v011 * wx1;
    float c10 = v100 * wx0 + v101 * wx1;
    float c11 = v110 * wx0 + v111 * wx1;

    float c0 = c00 * wy0 + c01 * wy1;
    float c1 = c10 * wy0 + c11 * wy1;

    out[i] = 100.0f * (c0 * wz0 + c1 * wz1);
}

extern "C" void kernel_launch(void* const* d_in, const int* in_sizes, int n_in,
                              void* d_out, int out_size, void* d_ws, size_t ws_size,
                              hipStream_t stream) {
    const float* x   = (const float*)d_in[0];   // [8, 65536, 3] fp32
    const float* vol = (const float*)d_in[1];   // [256,256,256] fp32
    float* out = (float*)d_out;                 // [8, 65536] fp32

    int n = out_size;  // 524288 points
    int block = 256;
    int grid = (n + block - 1) / block;
    VolumeExplicit_29257317220866_kernel<<<grid, block, 0, stream>>>(x, vol, out, n);
}

// Round 2
// 119.511 us; speedup vs baseline: 1.0101x; 1.0101x over previous
//
#include <hip/hip_runtime.h>

// Trilinear grid_sample (align_corners=False, zeros padding) of 256^3 fp32
// volume, scaled by 100. Round 2: 2 points/thread to double per-wave MLP
// (16 volume loads in flight before first use); nontemporal coord/out
// accesses to keep L2 for volume lines.

#define RES 256

__device__ __forceinline__ void point_setup(
    const float* __restrict__ x, int i,
    int& r00, int& r01, int& r10, int& r11, int& xc0, int& xc1,
    float& wx0, float& wx1, float& wy0, float& wy1, float& wz0, float& wz1)
{
    float gx = __builtin_nontemporal_load(&x[3 * i + 0]) * 2.0f;
    float gy = __builtin_nontemporal_load(&x[3 * i + 1]) * 2.0f;
    float gz = __builtin_nontemporal_load(&x[3 * i + 2]) * 2.0f;

    float ix = ((gx + 1.0f) * (float)RES - 1.0f) * 0.5f;
    float iy = ((gy + 1.0f) * (float)RES - 1.0f) * 0.5f;
    float iz = ((gz + 1.0f) * (float)RES - 1.0f) * 0.5f;

    float x0f = floorf(ix), y0f = floorf(iy), z0f = floorf(iz);
    float tx = ix - x0f, ty = iy - y0f, tz = iz - z0f;

    int x0 = (int)x0f, y0 = (int)y0f, z0 = (int)z0f;
    int x1 = x0 + 1, y1 = y0 + 1, z1 = z0 + 1;

    wx0 = (x0 >= 0 && x0 < RES) ? (1.0f - tx) : 0.0f;
    wx1 = (x1 >= 0 && x1 < RES) ? tx : 0.0f;
    wy0 = (y0 >= 0 && y0 < RES) ? (1.0f - ty) : 0.0f;
    wy1 = (y1 >= 0 && y1 < RES) ? ty : 0.0f;
    wz0 = (z0 >= 0 && z0 < RES) ? (1.0f - tz) : 0.0f;
    wz1 = (z1 >= 0 && z1 < RES) ? tz : 0.0f;

    xc0 = min(max(x0, 0), RES - 1); xc1 = min(max(x1, 0), RES - 1);
    int yc0 = min(max(y0, 0), RES - 1), yc1 = min(max(y1, 0), RES - 1);
    int zc0 = min(max(z0, 0), RES - 1), zc1 = min(max(z1, 0), RES - 1);

    r00 = (zc0 * RES + yc0) * RES;
    r01 = (zc0 * RES + yc1) * RES;
    r10 = (zc1 * RES + yc0) * RES;
    r11 = (zc1 * RES + yc1) * RES;
}

__device__ __forceinline__ float trilerp(
    const float* __restrict__ vol,
    int r00, int r01, int r10, int r11, int xc0, int xc1,
    float wx0, float wx1, float wy0, float wy1, float wz0, float wz1)
{
    float v000 = vol[r00 + xc0];
    float v001 = vol[r00 + xc1];
    float v010 = vol[r01 + xc0];
    float v011 = vol[r01 + xc1];
    float v100 = vol[r10 + xc0];
    float v101 = vol[r10 + xc1];
    float v110 = vol[r11 + xc0];
    float v111 = vol[r11 + xc1];

    float c00 = v000 * wx0 + v001 * wx1;
    float c01 = v010 * wx0 + v011 * wx1;
    float c10 = v100 * wx0 + v101 * wx1;
    float c11 = v110 * wx0 + v111 * wx1;
    float c0 = c00 * wy0 + c01 * wy1;
    float c1 = c10 * wy0 + c11 * wy1;
    return 100.0f * (c0 * wz0 + c1 * wz1);
}

__global__ __launch_bounds__(256) void VolumeExplicit_29257317220866_kernel(
    const float* __restrict__ x,
    const float* __restrict__ vol,
    float* __restrict__ out,
    int n)
{
    int tid = blockIdx.x * blockDim.x + threadIdx.x;
    int half = n >> 1;
    if (tid >= half) return;
    int iA = tid;
    int iB = tid + half;

    // setup both points first (addresses + weights), then issue all 16
    // volume loads back-to-back so they are in flight together.
    int a_r00, a_r01, a_r10, a_r11, a_x0, a_x1;
    float a_wx0, a_wx1, a_wy0, a_wy1, a_wz0, a_wz1;
    point_setup(x, iA, a_r00, a_r01, a_r10, a_r11, a_x0, a_x1,
                a_wx0, a_wx1, a_wy0, a_wy1, a_wz0, a_wz1);

    int b_r00, b_r01, b_r10, b_r11, b_x0, b_x1;
    float b_wx0, b_wx1, b_wy0, b_wy1, b_wz0, b_wz1;
    point_setup(x, iB, b_r00, b_r01, b_r10, b_r11, b_x0, b_x1,
                b_wx0, b_wx1, b_wy0, b_wy1, b_wz0, b_wz1);

    float oA = trilerp(vol, a_r00, a_r01, a_r10, a_r11, a_x0, a_x1,
                       a_wx0, a_wx1, a_wy0, a_wy1, a_wz0, a_wz1);
    float oB = trilerp(vol, b_r00, b_r01, b_r10, b_r11, b_x0, b_x1,
                       b_wx0, b_wx1, b_wy0, b_wy1, b_wz0, b_wz1);

    __builtin_nontemporal_store(oA, &out[iA]);
    __builtin_nontemporal_store(oB, &out[iB]);
}

extern "C" void kernel_launch(void* const* d_in, const int* in_sizes, int n_in,
                              void* d_out, int out_size, void* d_ws, size_t ws_size,
                              hipStream_t stream) {
    const float* x   = (const float*)d_in[0];   // [8, 65536, 3] fp32
    const float* vol = (const float*)d_in[1];   // [256,256,256] fp32
    float* out = (float*)d_out;                 // [8, 65536] fp32

    int n = out_size;          // 524288 points
    int half = n >> 1;         // 2 points per thread
    int block = 256;
    int grid = (half + block - 1) / block;   // 1024 blocks
    VolumeExplicit_29257317220866_kernel<<<grid, block, 0, stream>>>(x, vol, out, n);
}